// Round 2
// baseline (541.969 us; speedup 1.0000x reference)
//
#include <hip/hip_runtime.h>

#define THETA_DIM 11
#define BQ   16      // chains per block (block = 1 wave, 4 lanes per chain)
#define TILE 64      // output steps staged per LDS writeback tile
#define OPAD 68      // padded LDS row stride (floats)

// ---- quad (4-lane) cross-lane via DPP quad_perm (VALU pipe) ----
__device__ __forceinline__ float qdpp_b1(float v) {   // [1,0,3,2]
  return __builtin_bit_cast(float,
      __builtin_amdgcn_update_dpp(0, __builtin_bit_cast(int, v), 0xB1, 0xF, 0xF, true));
}
__device__ __forceinline__ float qdpp_4e(float v) {   // [2,3,0,1]
  return __builtin_bit_cast(float,
      __builtin_amdgcn_update_dpp(0, __builtin_bit_cast(int, v), 0x4E, 0xF, 0xF, true));
}
__device__ __forceinline__ float quad_max(float v) {
  v = fmaxf(v, qdpp_b1(v)); v = fmaxf(v, qdpp_4e(v)); return v;
}
__device__ __forceinline__ float quad_min(float v) {
  v = fminf(v, qdpp_b1(v)); v = fminf(v, qdpp_4e(v)); return v;
}
__device__ __forceinline__ float quad_sum(float v) {
  v = v + qdpp_b1(v); v = v + qdpp_4e(v); return v;
}

// One recurrence step. Critical path: x1 -> A -> (cmp,cndmask) -> mul -> exp2
// -> p*cc -> 2 DPP adds -> rcp -> fma -> x. Everything else (q, qmax/qmin,
// dq, c1, cc) derives from one-step-older state and schedules into the gaps.
__device__ __forceinline__ float bh_step(
    float es, float& x1, float& x2,
    float& c1, float& dqM, float& dqm, float& cc,
    float bl2e, float bl2eR, float negR, float g, float bb,
    float gR, float bR) {
  const float A  = fmaf(bl2e, x1, -c1);          // beta*log2e*(x1 - R*x2)
  const float dq = (A >= 0.0f) ? dqM : dqm;      // selects max_k(A*q_k)
  const float t  = A * dq;                       // tj - m, always <= 0
  const float p  = __builtin_amdgcn_exp2f(t);    // max lane -> exactly 1
  const float pc = p * cc;
  const float num = quad_sum(pc);
  const float den = quad_sum(p);                 // in [1,4]
  const float x  = fmaf(num, __builtin_amdgcn_rcpf(den), es);
  // ---- off-critical-path precompute for NEXT step ----
  // next x2 = x1, next x3 = x2 (both known now, before the shift)
  const float qn  = fmaf(negR, x1, fmaf(g, x2, bb));  // g*x3' + b - R*x2'
  const float c1n = bl2eR * x1;                       // beta*log2e*R*x2'
  const float qmaxn = quad_max(qn);
  const float qminn = quad_min(qn);
  dqM = qn - qmaxn;
  dqm = qn - qminn;
  c1  = c1n;
  x2  = x1; x1 = x;
  cc  = fmaf(gR, x, bR);                          // (g*x1' + b)/R for next step
  return x;
}

__global__ void __launch_bounds__(64, 1)
bh_kernel(const float* __restrict__ theta, const float* __restrict__ eps,
          float* __restrict__ out, int Tn) {
  __shared__ float out_s[BQ][OPAD];   // output staging tile only

  const int lane = threadIdx.x;
  const int c  = lane >> 2;          // chain within block (0..15)
  const int j  = lane & 3;           // softmax component (0..3)
  const int cb = blockIdx.x * BQ;
  const int b  = cb + c;

  const float* th = theta + b * THETA_DIM;
  const float beta = th[0];
  const float g    = th[1 + j];
  const float bb   = th[5 + j];
  const float sig  = th[9];
  const float r    = th[10];
  const float R    = 1.0f + r;
  const float invR = 1.0f / R;
  const float L2E  = 1.4426950408889634f;
  const float bl2e  = beta * L2E;
  const float bl2eR = bl2e * R;
  const float negR  = -R;
  const float gR = g * invR;
  const float bR = bb * invR;
  const float sR = sig * invR;

  // initial state x1=x2=x3=0
  float x1 = 0.f, x2 = 0.f;
  float c1 = 0.f;
  float q0 = bb;                       // g*0 + b - R*0
  float qmax0 = quad_max(q0), qmin0 = quad_min(q0);
  float dqM = q0 - qmax0, dqm = q0 - qmin0;
  float cc = bR;

  // eps: direct global loads per quad, 2-group register prefetch pipeline
  const float* ep = eps + (size_t)b * Tn;
  const int tlast = Tn - 4;
  float4 eA = *(const float4*)(ep + 0);
  float4 eB = *(const float4*)(ep + 4);

  // output writeback lane mapping: 16 lanes x float4 cover one row
  const int col  = lane & 15;
  const int rsub = lane >> 4;

  const bool j0 = (j == 0), j1 = (j == 1), j2 = (j == 2);

  int t = 0;
  const int NT = Tn / TILE;
  for (int tile = 0; tile < NT; ++tile) {
    float* oc = &out_s[c][0];

    #pragma unroll 4
    for (int g4 = 0; g4 < TILE / 4; ++g4) {
      const float4 ecur = eA;
      eA = eB;
      int tn = t + 8; tn = (tn > tlast) ? tlast : tn;
      eB = *(const float4*)(ep + tn);                 // ~550 cy ahead of use
      const float es0 = ecur.x * sR, es1 = ecur.y * sR;
      const float es2 = ecur.z * sR, es3 = ecur.w * sR;

      const float xw0 = bh_step(es0, x1,x2, c1,dqM,dqm,cc, bl2e,bl2eR,negR,g,bb,gR,bR);
      const float xw1 = bh_step(es1, x1,x2, c1,dqM,dqm,cc, bl2e,bl2eR,negR,g,bb,gR,bR);
      const float xw2 = bh_step(es2, x1,x2, c1,dqM,dqm,cc, bl2e,bl2eR,negR,g,bb,gR,bR);
      const float xw3 = bh_step(es3, x1,x2, c1,dqM,dqm,cc, bl2e,bl2eR,negR,g,bb,gR,bR);

      const float xw = j0 ? xw0 : (j1 ? xw1 : (j2 ? xw2 : xw3));
      oc[g4 * 4 + j] = xw;            // lane j stores step 4*g4+j
      t += 4;
    }

    // coalesced float4 writeback of the 16x64 output tile
    const int t0 = tile * TILE;
    #pragma unroll
    for (int i = 0; i < 4; ++i) {
      const float4 o4 = *(const float4*)&out_s[i*4 + rsub][col*4];
      *(float4*)(out + (size_t)(cb + i*4 + rsub) * Tn + t0 + col*4) = o4;
    }
  }
}

extern "C" void kernel_launch(void* const* d_in, const int* in_sizes, int n_in,
                              void* d_out, int out_size, void* d_ws, size_t ws_size,
                              hipStream_t stream) {
  const float* theta = (const float*)d_in[0];
  const float* eps   = (const float*)d_in[1];
  float* out = (float*)d_out;
  const int B  = in_sizes[0] / THETA_DIM;   // 8192
  const int Tn = in_sizes[1] / B;           // 4096
  const int blocks = B / BQ;                // 512 single-wave blocks
  bh_kernel<<<blocks, 64, 0, stream>>>(theta, eps, out, Tn);
}

// Round 3
// 491.446 us; speedup vs baseline: 1.1028x; 1.1028x over previous
//
#include <hip/hip_runtime.h>

#define THETA_DIM 11

typedef float v2f __attribute__((ext_vector_type(2)));

__device__ __forceinline__ v2f v2(float s) { return (v2f){s, s}; }

// One chain per lane. All 4 softmax components in-lane via packed f32 ops.
// No cross-lane, no LDS. Critical path per step:
//   x1 -> A(fma) -> uv(pk_mul) -> m(max) -> e(pk_fma) -> exp2 -> pk_mul ->
//   pk_fma -> hadd -> rcp -> fma -> x     (~10 VALU deps)
// Everything else (q', qmax/qmin, m1', c', es) derives from one-step-older
// state and fills the issue gaps.
__global__ void __launch_bounds__(64, 1)
bh_kernel(const float* __restrict__ theta, const float* __restrict__ eps,
          float* __restrict__ out, int Tn) {
  const int b = blockIdx.x * 64 + threadIdx.x;

  const float* th = theta + (size_t)b * THETA_DIM;
  const float beta = th[0];
  const v2f g01 = {th[1], th[2]}, g23 = {th[3], th[4]};
  const v2f b01 = {th[5], th[6]}, b23 = {th[7], th[8]};
  const float sig = th[9];
  const float R   = 1.0f + th[10];
  const float invR = 1.0f / R;
  const float L2E  = 1.4426950408889634f;
  const float bl2e  = beta * L2E;
  const float bl2eR = bl2e * R;
  const float sR    = sig * invR;
  const v2f gR01 = g01 * v2(invR), gR23 = g23 * v2(invR);
  const v2f bR01 = b01 * v2(invR), bR23 = b23 * v2(invR);
  const v2f nR   = v2(-R);

  // state (x1=x2=x3=0)
  float x1 = 0.f, x2 = 0.f;
  float m1 = 0.f;                 // bl2eR * x2
  v2f q01 = b01, q23 = b23;       // g*x3 + b - R*x2
  v2f c01 = bR01, c23 = bR23;     // (g*x1 + b)/R
  v2f qmm;                        // (qmax, qmin)
  {
    v2f mx = __builtin_elementwise_max(q01, q23);
    v2f mn = __builtin_elementwise_min(q01, q23);
    qmm = (v2f){fmaxf(mx.x, mx.y), fminf(mn.x, mn.y)};
  }

  auto step = [&](float e) -> float {
    // ---- on-path ----
    const float A  = fmaf(bl2e, x1, -m1);          // beta*l2e*(x1 - R*x2)
    const v2f  uv  = v2(A) * qmm;                  // {A*qmax, A*qmin}
    const float m  = fmaxf(uv.x, uv.y);            // = max_j(A*q_j), branchless
    const v2f  e01 = __builtin_elementwise_fma(v2(A), q01, v2(-m));
    const v2f  e23 = __builtin_elementwise_fma(v2(A), q23, v2(-m));
    const v2f  p01 = {__builtin_amdgcn_exp2f(e01.x), __builtin_amdgcn_exp2f(e01.y)};
    const v2f  p23 = {__builtin_amdgcn_exp2f(e23.x), __builtin_amdgcn_exp2f(e23.y)};
    // ---- off-path: next-step precompute from pre-shift state ----
    const v2f  w01  = __builtin_elementwise_fma(g01, v2(x2), b01);  // g*x3' + b
    const v2f  w23  = __builtin_elementwise_fma(g23, v2(x2), b23);
    const v2f  q01n = __builtin_elementwise_fma(nR, v2(x1), w01);   // - R*x2'
    const v2f  q23n = __builtin_elementwise_fma(nR, v2(x1), w23);
    const v2f  mxv  = __builtin_elementwise_max(q01n, q23n);
    const v2f  mnv  = __builtin_elementwise_min(q01n, q23n);
    const float m1n = bl2eR * x1;
    // ---- on-path finish ----
    const v2f  nv  = __builtin_elementwise_fma(p23, c23, p01 * c01);
    const float num = nv.x + nv.y;
    const v2f  dv  = p01 + p23;
    const float den = dv.x + dv.y;                 // in [1,4]
    const float x  = fmaf(num, __builtin_amdgcn_rcpf(den), e * sR);
    // ---- shift + next-step c (short slack path off new x) ----
    x2 = x1; x1 = x;
    m1 = m1n; q01 = q01n; q23 = q23n;
    qmm = (v2f){fmaxf(mxv.x, mxv.y), fminf(mnv.x, mnv.y)};
    c01 = __builtin_elementwise_fma(gR01, v2(x), bR01);
    c23 = __builtin_elementwise_fma(gR23, v2(x), bR23);
    return x;
  };

  const float* ep = eps + (size_t)b * Tn;
  float* op = out + (size_t)b * Tn;

  // eps register pipeline: 16-float blocks, 2 blocks (~32 steps ~ 2000 cy) deep
  float4 cA[4], cB[4], cC[4];
  #pragma unroll
  for (int i = 0; i < 4; ++i) cA[i] = *(const float4*)(ep + i * 4);
  #pragma unroll
  for (int i = 0; i < 4; ++i) cB[i] = *(const float4*)(ep + 16 + i * 4);

  const int NB = Tn / 16;
  int t0 = 0;
  for (int blk = 0; blk < NB; ++blk) {
    int tl = t0 + 32;
    if (tl > Tn - 16) tl = Tn - 16;
    const float* lp = ep + tl;
    #pragma unroll
    for (int i = 0; i < 4; ++i) cC[i] = *(const float4*)(lp + i * 4);

    #pragma unroll
    for (int i = 0; i < 4; ++i) {
      float4 o;
      o.x = step(cA[i].x);
      o.y = step(cA[i].y);
      o.z = step(cA[i].z);
      o.w = step(cA[i].w);
      *(float4*)(op + t0 + i * 4) = o;   // per-lane row store; L2 write-combines
    }

    #pragma unroll
    for (int i = 0; i < 4; ++i) { cA[i] = cB[i]; cB[i] = cC[i]; }
    t0 += 16;
  }
}

extern "C" void kernel_launch(void* const* d_in, const int* in_sizes, int n_in,
                              void* d_out, int out_size, void* d_ws, size_t ws_size,
                              hipStream_t stream) {
  const float* theta = (const float*)d_in[0];
  const float* eps   = (const float*)d_in[1];
  float* out = (float*)d_out;
  const int B  = in_sizes[0] / THETA_DIM;   // 8192
  const int Tn = in_sizes[1] / B;           // 4096
  const int blocks = B / 64;                // 128 single-wave blocks, 1 chain/lane
  bh_kernel<<<blocks, 64, 0, stream>>>(theta, eps, out, Tn);
}